// Round 6
// baseline (414.213 us; speedup 1.0000x reference)
//
#include <hip/hip_runtime.h>
#include <hip/hip_bf16.h>

#define N_NODES 50000
#define N_EDGES 600000
#define DIM 128
#define N_GRAPHS 64
#define CAP 64            // padded CSR row capacity (mean deg 12; P(deg>=64)~0)
#define CAP_SHIFT 6

typedef __bf16 bf16x8 __attribute__((ext_vector_type(8)));
typedef float f32x4 __attribute__((ext_vector_type(4)));

// round-to-nearest-even fp32 -> bf16 (as ushort)
__device__ __forceinline__ unsigned short f2bf(float f) {
    unsigned int u = __float_as_uint(f);
    u += 0x7FFFu + ((u >> 16) & 1u);
    return (unsigned short)(u >> 16);
}
__device__ __forceinline__ float bflo(unsigned int u) {   // low bf16 of packed pair
    return __uint_as_float(u << 16);
}
__device__ __forceinline__ float bfhi(unsigned int u) {   // high bf16
    return __uint_as_float(u & 0xFFFF0000u);
}

// ---------------------------------------------------------------------------
// zero all accumulators in one launch (replaces 4 hipMemsetAsync)
// ---------------------------------------------------------------------------
__global__ __launch_bounds__(256) void zero_kernel(int* __restrict__ deg_out,
                                                   int* __restrict__ cnt_in,
                                                   float* __restrict__ gsum,
                                                   float* __restrict__ gcnt) {
    int i = blockIdx.x * blockDim.x + threadIdx.x;
    if (i < N_NODES) { deg_out[i] = 0; cnt_in[i] = 0; }
    if (i < N_GRAPHS * DIM) gsum[i] = 0.f;
    if (i < N_GRAPHS) gcnt[i] = 0.f;
}

// ---------------------------------------------------------------------------
// fused CSR build: one pass over edges (slots are ushort: node ids < 65536)
// ---------------------------------------------------------------------------
__global__ __launch_bounds__(256) void build_kernel(const int* __restrict__ src,
                                                    const int* __restrict__ dst,
                                                    int* __restrict__ deg_out,
                                                    int* __restrict__ cnt_in,
                                                    unsigned short* __restrict__ slots, int ne) {
    int e = blockIdx.x * blockDim.x + threadIdx.x;
    if (e < ne) {
        int s = src[e];
        int d = dst[e];
        atomicAdd(&deg_out[s], 1);
        int p = atomicAdd(&cnt_in[d], 1);
        if (p < CAP) slots[(d << CAP_SHIFT) + p] = (unsigned short)s;
    }
}

// ---------------------------------------------------------------------------
// prep: norms (i < N_NODES) + conv_W -> bf16 TRANSPOSED WT[l][n][k] (i < 4*128*128)
// ---------------------------------------------------------------------------
__global__ __launch_bounds__(256) void prep_kernel(const int* __restrict__ deg_out,
                                                   const int* __restrict__ deg_in,
                                                   float* __restrict__ norm_src,
                                                   float* __restrict__ norm_dst,
                                                   const float* __restrict__ w,
                                                   unsigned short* __restrict__ wt) {
    int i = blockIdx.x * blockDim.x + threadIdx.x;
    if (i < N_NODES) {
        norm_src[i] = 1.0f / sqrtf(fmaxf((float)deg_out[i], 1.0f));
        norm_dst[i] = 1.0f / sqrtf(fmaxf((float)deg_in[i], 1.0f));
    }
    if (i < 4 * DIM * DIM) {
        int l = i >> 14;           // layer
        int j = i & 16383;
        int k = j >> 7;
        int n = j & 127;
        wt[(l << 14) + n * DIM + k] = f2bf(w[i]);
    }
}

// ---------------------------------------------------------------------------
// xs = bf16( x * norm_src[row] )   (8 floats per thread)
// ---------------------------------------------------------------------------
__global__ __launch_bounds__(256) void scale_x_kernel(const float* __restrict__ x,
                                                      const float* __restrict__ norm_src,
                                                      unsigned short* __restrict__ xs) {
    int i = blockIdx.x * blockDim.x + threadIdx.x;     // 8-float chunk index
    if (i >= N_NODES * (DIM / 8)) return;
    int row = i >> 4;                                   // 16 chunks per row
    float ns = norm_src[row];
    const float4* px = (const float4*)(x + (size_t)i * 8);
    float4 v0 = px[0], v1 = px[1];
    uint4 o;
    o.x = (unsigned)f2bf(v0.x * ns) | ((unsigned)f2bf(v0.y * ns) << 16);
    o.y = (unsigned)f2bf(v0.z * ns) | ((unsigned)f2bf(v0.w * ns) << 16);
    o.z = (unsigned)f2bf(v1.x * ns) | ((unsigned)f2bf(v1.y * ns) << 16);
    o.w = (unsigned)f2bf(v1.z * ns) | ((unsigned)f2bf(v1.w * ns) << 16);
    *(uint4*)(xs + (size_t)i * 8) = o;
}

// ---------------------------------------------------------------------------
// SpMM (bf16 h): out[d] = bf16( norm_dst[d] * sum_{s in in(d)} h[s] )
// wave = 4 edge-slots x 16 sub-lanes; sub covers 8 bf16 (16B); 4x unrolled
// -> 16 edges (4KB) in flight per wave iteration
// ---------------------------------------------------------------------------
__global__ __launch_bounds__(256) void spmm_kernel(const int* __restrict__ cnt_in,
                                                   const unsigned short* __restrict__ slots,
                                                   const unsigned short* __restrict__ h,
                                                   const float* __restrict__ norm_dst,
                                                   unsigned short* __restrict__ out) {
    int node = blockIdx.x * 4 + (threadIdx.x >> 6);
    if (node >= N_NODES) return;
    int lane = threadIdx.x & 63;
    int slot = lane >> 4;          // 0..3 : which edge in the group
    int sub  = lane & 15;          // bf16 chunk: sub*8 .. sub*8+7
    int beg = node << CAP_SHIFT;
    int cnt = cnt_in[node];
    if (cnt > CAP) cnt = CAP;
    int end = beg + cnt;
    float a[8] = {}, b[8] = {}, c[8] = {}, d[8] = {};
    const unsigned short* hp = h + sub * 8;
    for (int base = beg; base < end; base += 16) {
        int e0 = base + slot;
        if (e0 < end) {
            uint4 v = *(const uint4*)(hp + (size_t)slots[e0] * DIM);
            a[0] += bflo(v.x); a[1] += bfhi(v.x); a[2] += bflo(v.y); a[3] += bfhi(v.y);
            a[4] += bflo(v.z); a[5] += bfhi(v.z); a[6] += bflo(v.w); a[7] += bfhi(v.w);
        }
        if (e0 + 4 < end) {
            uint4 v = *(const uint4*)(hp + (size_t)slots[e0 + 4] * DIM);
            b[0] += bflo(v.x); b[1] += bfhi(v.x); b[2] += bflo(v.y); b[3] += bfhi(v.y);
            b[4] += bflo(v.z); b[5] += bfhi(v.z); b[6] += bflo(v.w); b[7] += bfhi(v.w);
        }
        if (e0 + 8 < end) {
            uint4 v = *(const uint4*)(hp + (size_t)slots[e0 + 8] * DIM);
            c[0] += bflo(v.x); c[1] += bfhi(v.x); c[2] += bflo(v.y); c[3] += bfhi(v.y);
            c[4] += bflo(v.z); c[5] += bfhi(v.z); c[6] += bflo(v.w); c[7] += bfhi(v.w);
        }
        if (e0 + 12 < end) {
            uint4 v = *(const uint4*)(hp + (size_t)slots[e0 + 12] * DIM);
            d[0] += bflo(v.x); d[1] += bfhi(v.x); d[2] += bflo(v.y); d[3] += bfhi(v.y);
            d[4] += bflo(v.z); d[5] += bfhi(v.z); d[6] += bflo(v.w); d[7] += bfhi(v.w);
        }
    }
    #pragma unroll
    for (int j = 0; j < 8; j++) {
        a[j] += b[j]; c[j] += d[j]; a[j] += c[j];
        a[j] += __shfl_xor(a[j], 16);
        a[j] += __shfl_xor(a[j], 32);
    }
    if (slot == 0) {
        float nd = norm_dst[node];
        uint4 o;
        o.x = (unsigned)f2bf(a[0] * nd) | ((unsigned)f2bf(a[1] * nd) << 16);
        o.y = (unsigned)f2bf(a[2] * nd) | ((unsigned)f2bf(a[3] * nd) << 16);
        o.z = (unsigned)f2bf(a[4] * nd) | ((unsigned)f2bf(a[5] * nd) << 16);
        o.w = (unsigned)f2bf(a[6] * nd) | ((unsigned)f2bf(a[7] * nd) << 16);
        *(uint4*)(out + (size_t)node * DIM + sub * 8) = o;
    }
}

// ---------------------------------------------------------------------------
// GEMM via MFMA bf16: C[N,128] = A[N,128] @ W[128,128] (+bias, relu, row_scale)
// W passed TRANSPOSED (WT[n][k]) so B-fragments are contiguous 16B loads.
// one wave per 16-row tile; 8 col-tiles x 4 k-steps
//   A: lane holds A[m=lane&15][k=(lane>>4)*8+j]   (16B contiguous)
//   B: lane holds B[k=(lane>>4)*8+j][n=lane&15] = WT[n][k..k+8)  (16B contiguous)
//   C: c[reg] = C[row=(lane>>4)*4+reg][col=lane&15]
// ---------------------------------------------------------------------------
__global__ __launch_bounds__(256) void gemm_mfma_kernel(const unsigned short* __restrict__ A,
                                                        const unsigned short* __restrict__ WT,
                                                        const float* __restrict__ bias,
                                                        unsigned short* __restrict__ C,
                                                        const float* __restrict__ row_scale,
                                                        int do_relu) {
    int wave = threadIdx.x >> 6;
    int lane = threadIdx.x & 63;
    int tile = blockIdx.x * 4 + wave;            // 0..3124
    if (tile >= N_NODES / 16) return;
    int r0 = tile * 16;
    int quad = lane >> 4;
    int l15 = lane & 15;

    f32x4 acc[8];
    #pragma unroll
    for (int ct = 0; ct < 8; ct++) {
        float bv = bias[ct * 16 + l15];
        acc[ct] = (f32x4){bv, bv, bv, bv};
    }

    #pragma unroll
    for (int ks = 0; ks < 4; ks++) {
        bf16x8 af = *(const bf16x8*)(A + (size_t)(r0 + l15) * DIM + ks * 32 + quad * 8);
        #pragma unroll
        for (int ct = 0; ct < 8; ct++) {
            bf16x8 bf = *(const bf16x8*)(WT + (size_t)(ct * 16 + l15) * DIM + ks * 32 + quad * 8);
            acc[ct] = __builtin_amdgcn_mfma_f32_16x16x32_bf16(af, bf, acc[ct], 0, 0, 0);
        }
    }

    #pragma unroll
    for (int ct = 0; ct < 8; ct++) {
        #pragma unroll
        for (int reg = 0; reg < 4; reg++) {
            int r = r0 + quad * 4 + reg;
            float v = acc[ct][reg];
            if (do_relu) v = fmaxf(v, 0.f);
            if (row_scale) v *= row_scale[r];
            C[(size_t)r * DIM + ct * 16 + l15] = f2bf(v);
        }
    }
}

// ---------------------------------------------------------------------------
// mean-pool over bf16 h (graph_id sorted): 8 groups of 32 lanes per block,
// lane covers 4 bf16 (8B); fp32 accumulate; atomic flush on graph boundary
// ---------------------------------------------------------------------------
#define POOL_NPG 32
__global__ __launch_bounds__(256) void pool_kernel(const unsigned short* __restrict__ h,
                                                   const int* __restrict__ graph_id,
                                                   float* __restrict__ gsum,
                                                   float* __restrict__ gcnt, int n) {
    int group = threadIdx.x >> 5;
    int lane = threadIdx.x & 31;
    int base = (blockIdx.x * 8 + group) * POOL_NPG;
    if (base >= n) return;
    int end = base + POOL_NPG;
    if (end > n) end = n;
    float4 acc = {0.f, 0.f, 0.f, 0.f};
    int cur = graph_id[base];
    int cnt = 0;
    for (int i = base; i < end; i++) {
        int g = graph_id[i];
        if (g != cur) {
            float* p = gsum + cur * DIM + lane * 4;
            atomicAdd(p + 0, acc.x); atomicAdd(p + 1, acc.y);
            atomicAdd(p + 2, acc.z); atomicAdd(p + 3, acc.w);
            if (lane == 0) atomicAdd(&gcnt[cur], (float)cnt);
            acc = {0.f, 0.f, 0.f, 0.f}; cnt = 0; cur = g;
        }
        uint2 v = *(const uint2*)(h + (size_t)i * DIM + lane * 4);
        acc.x += bflo(v.x); acc.y += bfhi(v.x);
        acc.z += bflo(v.y); acc.w += bfhi(v.y);
        cnt++;
    }
    float* p = gsum + cur * DIM + lane * 4;
    atomicAdd(p + 0, acc.x); atomicAdd(p + 1, acc.y);
    atomicAdd(p + 2, acc.z); atomicAdd(p + 3, acc.w);
    if (lane == 0) atomicAdd(&gcnt[cur], (float)cnt);
}

// ---------------------------------------------------------------------------
// FFNN head: one block per graph (fp32)
// ---------------------------------------------------------------------------
__global__ __launch_bounds__(128) void mlp_kernel(const float* __restrict__ gsum,
                                                  const float* __restrict__ gcnt,
                                                  const float* __restrict__ ffnn_W,
                                                  const float* __restrict__ ffnn_b,
                                                  const float* __restrict__ out_W,
                                                  const float* __restrict__ out_b,
                                                  float* __restrict__ out) {
    __shared__ float buf[DIM];
    __shared__ float red[DIM];
    int g = blockIdx.x;
    int t = threadIdx.x;
    float cnt = fmaxf(gcnt[g], 1.0f);
    buf[t] = gsum[g * DIM + t] / cnt;
    __syncthreads();
    for (int l = 0; l < 3; l++) {
        const float* W = ffnn_W + (size_t)l * DIM * DIM;
        float s = ffnn_b[l * DIM + t];
        for (int k = 0; k < DIM; k++) s += buf[k] * W[k * DIM + t];
        __syncthreads();
        buf[t] = fmaxf(s, 0.0f);
        __syncthreads();
    }
    float p = buf[t] * out_W[t];
    red[t] = p;
    __syncthreads();
    for (int off = 64; off > 0; off >>= 1) {
        if (t < off) red[t] += red[t + off];
        __syncthreads();
    }
    if (t == 0) out[g] = 1.0f / (1.0f + expf(-(red[0] + out_b[0])));
}

// ---------------------------------------------------------------------------
// launch
// ---------------------------------------------------------------------------
extern "C" void kernel_launch(void* const* d_in, const int* in_sizes, int n_in,
                              void* d_out, int out_size, void* d_ws, size_t ws_size,
                              hipStream_t stream) {
    const float* x        = (const float*)d_in[0];
    const int*   src      = (const int*)d_in[1];
    const int*   dst      = (const int*)d_in[2];
    const int*   graph_id = (const int*)d_in[3];
    const float* conv_W   = (const float*)d_in[4];
    const float* conv_b   = (const float*)d_in[5];
    const float* ffnn_W   = (const float*)d_in[6];
    const float* ffnn_b   = (const float*)d_in[7];
    const float* out_W    = (const float*)d_in[8];
    const float* out_b    = (const float*)d_in[9];
    float* out = (float*)d_out;

    char* w = (char*)d_ws;
    auto alloc = [&](size_t bytes) -> void* {
        void* p = (void*)w;
        w += (bytes + 255) & ~(size_t)255;
        return p;
    };
    int*   deg_out_i = (int*)alloc(N_NODES * sizeof(int));
    int*   cnt_in    = (int*)alloc(N_NODES * sizeof(int));
    float* norm_src  = (float*)alloc(N_NODES * sizeof(float));
    float* norm_dst  = (float*)alloc(N_NODES * sizeof(float));
    unsigned short* slots = (unsigned short*)alloc((size_t)N_NODES * CAP * sizeof(unsigned short));
    unsigned short* hA = (unsigned short*)alloc((size_t)N_NODES * DIM * sizeof(unsigned short));
    unsigned short* hB = (unsigned short*)alloc((size_t)N_NODES * DIM * sizeof(unsigned short));
    unsigned short* wbfT = (unsigned short*)alloc(4 * DIM * DIM * sizeof(unsigned short));
    float* gsum      = (float*)alloc(N_GRAPHS * DIM * sizeof(float));
    float* gcnt      = (float*)alloc(N_GRAPHS * sizeof(float));

    // zero accumulators (one launch)
    zero_kernel<<<(N_NODES + 255) / 256, 256, 0, stream>>>(deg_out_i, cnt_in, gsum, gcnt);

    // one-pass CSR build (padded buckets) + degrees
    build_kernel<<<(N_EDGES + 255) / 256, 256, 0, stream>>>(src, dst, deg_out_i, cnt_in, slots, N_EDGES);

    // norms + W->bf16 transposed
    prep_kernel<<<(4 * DIM * DIM + 255) / 256, 256, 0, stream>>>(deg_out_i, cnt_in, norm_src, norm_dst, conv_W, wbfT);

    // pre-scale x by norm_src -> hA (bf16); conv1..3 get the scale fused in gemm
    scale_x_kernel<<<(N_NODES * (DIM / 8) + 255) / 256, 256, 0, stream>>>(x, norm_src, hA);

    const int spmm_blocks = (N_NODES + 3) / 4;
    const int gemm_blocks = (N_NODES / 16 + 3) / 4;   // 3125 tiles / 4 waves

    // conv0: hA(scaled x) -> hB (spmm) -> hA (gemm, relu, *norm_src)
    spmm_kernel<<<spmm_blocks, 256, 0, stream>>>(cnt_in, slots, hA, norm_dst, hB);
    gemm_mfma_kernel<<<gemm_blocks, 256, 0, stream>>>(hB, wbfT + 0 * DIM * DIM, conv_b + 0 * DIM, hA, norm_src, 1);
    // conv1
    spmm_kernel<<<spmm_blocks, 256, 0, stream>>>(cnt_in, slots, hA, norm_dst, hB);
    gemm_mfma_kernel<<<gemm_blocks, 256, 0, stream>>>(hB, wbfT + 1 * DIM * DIM, conv_b + 1 * DIM, hA, norm_src, 1);
    // conv2
    spmm_kernel<<<spmm_blocks, 256, 0, stream>>>(cnt_in, slots, hA, norm_dst, hB);
    gemm_mfma_kernel<<<gemm_blocks, 256, 0, stream>>>(hB, wbfT + 2 * DIM * DIM, conv_b + 2 * DIM, hA, norm_src, 1);
    // conv3 (no relu, no scale)
    spmm_kernel<<<spmm_blocks, 256, 0, stream>>>(cnt_in, slots, hA, norm_dst, hB);
    gemm_mfma_kernel<<<gemm_blocks, 256, 0, stream>>>(hB, wbfT + 3 * DIM * DIM, conv_b + 3 * DIM, hA, (const float*)nullptr, 0);

    // mean pool + head
    pool_kernel<<<(N_NODES + 255) / 256, 256, 0, stream>>>(hA, graph_id, gsum, gcnt, N_NODES);
    mlp_kernel<<<N_GRAPHS, 128, 0, stream>>>(gsum, gcnt, ffnn_W, ffnn_b, out_W, out_b, out);
}

// Round 7
// 411.981 us; speedup vs baseline: 1.0054x; 1.0054x over previous
//
#include <hip/hip_runtime.h>
#include <hip/hip_bf16.h>

#define N_NODES 50000
#define N_EDGES 600000
#define DIM 128
#define N_GRAPHS 64
#define CAP 64            // padded CSR row capacity (mean deg 12; P(deg>=64)~0)
#define CAP_SHIFT 6

typedef __bf16 bf16x8 __attribute__((ext_vector_type(8)));
typedef float f32x4 __attribute__((ext_vector_type(4)));

// round-to-nearest-even fp32 -> bf16 (as ushort)
__device__ __forceinline__ unsigned short f2bf(float f) {
    unsigned int u = __float_as_uint(f);
    u += 0x7FFFu + ((u >> 16) & 1u);
    return (unsigned short)(u >> 16);
}
__device__ __forceinline__ float bflo(unsigned int u) {   // low bf16 of packed pair
    return __uint_as_float(u << 16);
}
__device__ __forceinline__ float bfhi(unsigned int u) {   // high bf16
    return __uint_as_float(u & 0xFFFF0000u);
}

// ---------------------------------------------------------------------------
// zero all accumulators in one launch (replaces 4 hipMemsetAsync)
// ---------------------------------------------------------------------------
__global__ __launch_bounds__(256) void zero_kernel(int* __restrict__ deg_out,
                                                   int* __restrict__ cnt_in,
                                                   float* __restrict__ gsum,
                                                   float* __restrict__ gcnt) {
    int i = blockIdx.x * blockDim.x + threadIdx.x;
    if (i < N_NODES) { deg_out[i] = 0; cnt_in[i] = 0; }
    if (i < N_GRAPHS * DIM) gsum[i] = 0.f;
    if (i < N_GRAPHS) gcnt[i] = 0.f;
}

// ---------------------------------------------------------------------------
// fused CSR build: one pass over edges (int slots: 4B stores are the native
// scattered-write grain; 2B ushort stores measured SLOWER — r6 regression)
// ---------------------------------------------------------------------------
__global__ __launch_bounds__(256) void build_kernel(const int* __restrict__ src,
                                                    const int* __restrict__ dst,
                                                    int* __restrict__ deg_out,
                                                    int* __restrict__ cnt_in,
                                                    int* __restrict__ slots, int ne) {
    int e = blockIdx.x * blockDim.x + threadIdx.x;
    if (e < ne) {
        int s = src[e];
        int d = dst[e];
        atomicAdd(&deg_out[s], 1);
        int p = atomicAdd(&cnt_in[d], 1);
        if (p < CAP) slots[(d << CAP_SHIFT) + p] = s;
    }
}

// ---------------------------------------------------------------------------
// prep: norms (i < N_NODES) + conv_W -> bf16 TRANSPOSED WT[l][n][k] (i < 4*128*128)
// ---------------------------------------------------------------------------
__global__ __launch_bounds__(256) void prep_kernel(const int* __restrict__ deg_out,
                                                   const int* __restrict__ deg_in,
                                                   float* __restrict__ norm_src,
                                                   float* __restrict__ norm_dst,
                                                   const float* __restrict__ w,
                                                   unsigned short* __restrict__ wt) {
    int i = blockIdx.x * blockDim.x + threadIdx.x;
    if (i < N_NODES) {
        norm_src[i] = 1.0f / sqrtf(fmaxf((float)deg_out[i], 1.0f));
        norm_dst[i] = 1.0f / sqrtf(fmaxf((float)deg_in[i], 1.0f));
    }
    if (i < 4 * DIM * DIM) {
        int l = i >> 14;           // layer
        int j = i & 16383;
        int k = j >> 7;
        int n = j & 127;
        wt[(l << 14) + n * DIM + k] = f2bf(w[i]);
    }
}

// ---------------------------------------------------------------------------
// xs = bf16( x * norm_src[row] )   (8 floats per thread)
// ---------------------------------------------------------------------------
__global__ __launch_bounds__(256) void scale_x_kernel(const float* __restrict__ x,
                                                      const float* __restrict__ norm_src,
                                                      unsigned short* __restrict__ xs) {
    int i = blockIdx.x * blockDim.x + threadIdx.x;     // 8-float chunk index
    if (i >= N_NODES * (DIM / 8)) return;
    int row = i >> 4;                                   // 16 chunks per row
    float ns = norm_src[row];
    const float4* px = (const float4*)(x + (size_t)i * 8);
    float4 v0 = px[0], v1 = px[1];
    uint4 o;
    o.x = (unsigned)f2bf(v0.x * ns) | ((unsigned)f2bf(v0.y * ns) << 16);
    o.y = (unsigned)f2bf(v0.z * ns) | ((unsigned)f2bf(v0.w * ns) << 16);
    o.z = (unsigned)f2bf(v1.x * ns) | ((unsigned)f2bf(v1.y * ns) << 16);
    o.w = (unsigned)f2bf(v1.z * ns) | ((unsigned)f2bf(v1.w * ns) << 16);
    *(uint4*)(xs + (size_t)i * 8) = o;
}

// ---------------------------------------------------------------------------
// SpMM (bf16 h): out[d] = bf16( norm_dst[d] * sum_{s in in(d)} h[s] )
// wave = 4 edge-slots x 16 sub-lanes; sub covers 8 bf16 (16B); 2x unrolled
// (8 edges in flight — the r5 measured-good config)
// ---------------------------------------------------------------------------
__global__ __launch_bounds__(256) void spmm_kernel(const int* __restrict__ cnt_in,
                                                   const int* __restrict__ slots,
                                                   const unsigned short* __restrict__ h,
                                                   const float* __restrict__ norm_dst,
                                                   unsigned short* __restrict__ out) {
    int node = blockIdx.x * 4 + (threadIdx.x >> 6);
    if (node >= N_NODES) return;
    int lane = threadIdx.x & 63;
    int slot = lane >> 4;          // 0..3 : which edge in the group
    int sub  = lane & 15;          // bf16 chunk: sub*8 .. sub*8+7
    int beg = node << CAP_SHIFT;
    int cnt = cnt_in[node];
    if (cnt > CAP) cnt = CAP;
    int end = beg + cnt;
    float a[8] = {}, b[8] = {};
    const unsigned short* hp = h + sub * 8;
    for (int base = beg; base < end; base += 8) {
        int e0 = base + slot;
        int e1 = e0 + 4;
        if (e0 < end) {
            uint4 v = *(const uint4*)(hp + (size_t)slots[e0] * DIM);
            a[0] += bflo(v.x); a[1] += bfhi(v.x); a[2] += bflo(v.y); a[3] += bfhi(v.y);
            a[4] += bflo(v.z); a[5] += bfhi(v.z); a[6] += bflo(v.w); a[7] += bfhi(v.w);
        }
        if (e1 < end) {
            uint4 v = *(const uint4*)(hp + (size_t)slots[e1] * DIM);
            b[0] += bflo(v.x); b[1] += bfhi(v.x); b[2] += bflo(v.y); b[3] += bfhi(v.y);
            b[4] += bflo(v.z); b[5] += bfhi(v.z); b[6] += bflo(v.w); b[7] += bfhi(v.w);
        }
    }
    #pragma unroll
    for (int j = 0; j < 8; j++) {
        a[j] += b[j];
        a[j] += __shfl_xor(a[j], 16);
        a[j] += __shfl_xor(a[j], 32);
    }
    if (slot == 0) {
        float nd = norm_dst[node];
        uint4 o;
        o.x = (unsigned)f2bf(a[0] * nd) | ((unsigned)f2bf(a[1] * nd) << 16);
        o.y = (unsigned)f2bf(a[2] * nd) | ((unsigned)f2bf(a[3] * nd) << 16);
        o.z = (unsigned)f2bf(a[4] * nd) | ((unsigned)f2bf(a[5] * nd) << 16);
        o.w = (unsigned)f2bf(a[6] * nd) | ((unsigned)f2bf(a[7] * nd) << 16);
        *(uint4*)(out + (size_t)node * DIM + sub * 8) = o;
    }
}

// ---------------------------------------------------------------------------
// GEMM via MFMA bf16: C[N,128] = A[N,128] @ W[128,128] (+bias, relu, row_scale)
// W passed TRANSPOSED (WT[n][k]) so B-fragments are contiguous 16B loads.
// ---------------------------------------------------------------------------
__global__ __launch_bounds__(256) void gemm_mfma_kernel(const unsigned short* __restrict__ A,
                                                        const unsigned short* __restrict__ WT,
                                                        const float* __restrict__ bias,
                                                        unsigned short* __restrict__ C,
                                                        const float* __restrict__ row_scale,
                                                        int do_relu) {
    int wave = threadIdx.x >> 6;
    int lane = threadIdx.x & 63;
    int tile = blockIdx.x * 4 + wave;            // 0..3124
    if (tile >= N_NODES / 16) return;
    int r0 = tile * 16;
    int quad = lane >> 4;
    int l15 = lane & 15;

    f32x4 acc[8];
    #pragma unroll
    for (int ct = 0; ct < 8; ct++) {
        float bv = bias[ct * 16 + l15];
        acc[ct] = (f32x4){bv, bv, bv, bv};
    }

    #pragma unroll
    for (int ks = 0; ks < 4; ks++) {
        bf16x8 af = *(const bf16x8*)(A + (size_t)(r0 + l15) * DIM + ks * 32 + quad * 8);
        #pragma unroll
        for (int ct = 0; ct < 8; ct++) {
            bf16x8 bf = *(const bf16x8*)(WT + (size_t)(ct * 16 + l15) * DIM + ks * 32 + quad * 8);
            acc[ct] = __builtin_amdgcn_mfma_f32_16x16x32_bf16(af, bf, acc[ct], 0, 0, 0);
        }
    }

    #pragma unroll
    for (int ct = 0; ct < 8; ct++) {
        #pragma unroll
        for (int reg = 0; reg < 4; reg++) {
            int r = r0 + quad * 4 + reg;
            float v = acc[ct][reg];
            if (do_relu) v = fmaxf(v, 0.f);
            if (row_scale) v *= row_scale[r];
            C[(size_t)r * DIM + ct * 16 + l15] = f2bf(v);
        }
    }
}

// ---------------------------------------------------------------------------
// mean-pool over bf16 h (graph_id sorted)
// ---------------------------------------------------------------------------
#define POOL_NPG 32
__global__ __launch_bounds__(256) void pool_kernel(const unsigned short* __restrict__ h,
                                                   const int* __restrict__ graph_id,
                                                   float* __restrict__ gsum,
                                                   float* __restrict__ gcnt, int n) {
    int group = threadIdx.x >> 5;
    int lane = threadIdx.x & 31;
    int base = (blockIdx.x * 8 + group) * POOL_NPG;
    if (base >= n) return;
    int end = base + POOL_NPG;
    if (end > n) end = n;
    float4 acc = {0.f, 0.f, 0.f, 0.f};
    int cur = graph_id[base];
    int cnt = 0;
    for (int i = base; i < end; i++) {
        int g = graph_id[i];
        if (g != cur) {
            float* p = gsum + cur * DIM + lane * 4;
            atomicAdd(p + 0, acc.x); atomicAdd(p + 1, acc.y);
            atomicAdd(p + 2, acc.z); atomicAdd(p + 3, acc.w);
            if (lane == 0) atomicAdd(&gcnt[cur], (float)cnt);
            acc = {0.f, 0.f, 0.f, 0.f}; cnt = 0; cur = g;
        }
        uint2 v = *(const uint2*)(h + (size_t)i * DIM + lane * 4);
        acc.x += bflo(v.x); acc.y += bfhi(v.x);
        acc.z += bflo(v.y); acc.w += bfhi(v.y);
        cnt++;
    }
    float* p = gsum + cur * DIM + lane * 4;
    atomicAdd(p + 0, acc.x); atomicAdd(p + 1, acc.y);
    atomicAdd(p + 2, acc.z); atomicAdd(p + 3, acc.w);
    if (lane == 0) atomicAdd(&gcnt[cur], (float)cnt);
}

// ---------------------------------------------------------------------------
// FFNN head: one block per graph (fp32)
// ---------------------------------------------------------------------------
__global__ __launch_bounds__(128) void mlp_kernel(const float* __restrict__ gsum,
                                                  const float* __restrict__ gcnt,
                                                  const float* __restrict__ ffnn_W,
                                                  const float* __restrict__ ffnn_b,
                                                  const float* __restrict__ out_W,
                                                  const float* __restrict__ out_b,
                                                  float* __restrict__ out) {
    __shared__ float buf[DIM];
    __shared__ float red[DIM];
    int g = blockIdx.x;
    int t = threadIdx.x;
    float cnt = fmaxf(gcnt[g], 1.0f);
    buf[t] = gsum[g * DIM + t] / cnt;
    __syncthreads();
    for (int l = 0; l < 3; l++) {
        const float* W = ffnn_W + (size_t)l * DIM * DIM;
        float s = ffnn_b[l * DIM + t];
        for (int k = 0; k < DIM; k++) s += buf[k] * W[k * DIM + t];
        __syncthreads();
        buf[t] = fmaxf(s, 0.0f);
        __syncthreads();
    }
    float p = buf[t] * out_W[t];
    red[t] = p;
    __syncthreads();
    for (int off = 64; off > 0; off >>= 1) {
        if (t < off) red[t] += red[t + off];
        __syncthreads();
    }
    if (t == 0) out[g] = 1.0f / (1.0f + expf(-(red[0] + out_b[0])));
}

// ---------------------------------------------------------------------------
// launch
// ---------------------------------------------------------------------------
extern "C" void kernel_launch(void* const* d_in, const int* in_sizes, int n_in,
                              void* d_out, int out_size, void* d_ws, size_t ws_size,
                              hipStream_t stream) {
    const float* x        = (const float*)d_in[0];
    const int*   src      = (const int*)d_in[1];
    const int*   dst      = (const int*)d_in[2];
    const int*   graph_id = (const int*)d_in[3];
    const float* conv_W   = (const float*)d_in[4];
    const float* conv_b   = (const float*)d_in[5];
    const float* ffnn_W   = (const float*)d_in[6];
    const float* ffnn_b   = (const float*)d_in[7];
    const float* out_W    = (const float*)d_in[8];
    const float* out_b    = (const float*)d_in[9];
    float* out = (float*)d_out;

    char* w = (char*)d_ws;
    auto alloc = [&](size_t bytes) -> void* {
        void* p = (void*)w;
        w += (bytes + 255) & ~(size_t)255;
        return p;
    };
    int*   deg_out_i = (int*)alloc(N_NODES * sizeof(int));
    int*   cnt_in    = (int*)alloc(N_NODES * sizeof(int));
    float* norm_src  = (float*)alloc(N_NODES * sizeof(float));
    float* norm_dst  = (float*)alloc(N_NODES * sizeof(float));
    int*   slots     = (int*)alloc((size_t)N_NODES * CAP * sizeof(int));
    unsigned short* hA = (unsigned short*)alloc((size_t)N_NODES * DIM * sizeof(unsigned short));
    unsigned short* hB = (unsigned short*)alloc((size_t)N_NODES * DIM * sizeof(unsigned short));
    unsigned short* wbfT = (unsigned short*)alloc(4 * DIM * DIM * sizeof(unsigned short));
    float* gsum      = (float*)alloc(N_GRAPHS * DIM * sizeof(float));
    float* gcnt     = (float*)alloc(N_GRAPHS * sizeof(float));

    // zero accumulators (one launch)
    zero_kernel<<<(N_NODES + 255) / 256, 256, 0, stream>>>(deg_out_i, cnt_in, gsum, gcnt);

    // one-pass CSR build (padded buckets) + degrees
    build_kernel<<<(N_EDGES + 255) / 256, 256, 0, stream>>>(src, dst, deg_out_i, cnt_in, slots, N_EDGES);

    // norms + W->bf16 transposed
    prep_kernel<<<(4 * DIM * DIM + 255) / 256, 256, 0, stream>>>(deg_out_i, cnt_in, norm_src, norm_dst, conv_W, wbfT);

    // pre-scale x by norm_src -> hA (bf16); conv1..3 get the scale fused in gemm
    scale_x_kernel<<<(N_NODES * (DIM / 8) + 255) / 256, 256, 0, stream>>>(x, norm_src, hA);

    const int spmm_blocks = (N_NODES + 3) / 4;
    const int gemm_blocks = (N_NODES / 16 + 3) / 4;   // 3125 tiles / 4 waves

    // conv0: hA(scaled x) -> hB (spmm) -> hA (gemm, relu, *norm_src)
    spmm_kernel<<<spmm_blocks, 256, 0, stream>>>(cnt_in, slots, hA, norm_dst, hB);
    gemm_mfma_kernel<<<gemm_blocks, 256, 0, stream>>>(hB, wbfT + 0 * DIM * DIM, conv_b + 0 * DIM, hA, norm_src, 1);
    // conv1
    spmm_kernel<<<spmm_blocks, 256, 0, stream>>>(cnt_in, slots, hA, norm_dst, hB);
    gemm_mfma_kernel<<<gemm_blocks, 256, 0, stream>>>(hB, wbfT + 1 * DIM * DIM, conv_b + 1 * DIM, hA, norm_src, 1);
    // conv2
    spmm_kernel<<<spmm_blocks, 256, 0, stream>>>(cnt_in, slots, hA, norm_dst, hB);
    gemm_mfma_kernel<<<gemm_blocks, 256, 0, stream>>>(hB, wbfT + 2 * DIM * DIM, conv_b + 2 * DIM, hA, norm_src, 1);
    // conv3 (no relu, no scale)
    spmm_kernel<<<spmm_blocks, 256, 0, stream>>>(cnt_in, slots, hA, norm_dst, hB);
    gemm_mfma_kernel<<<gemm_blocks, 256, 0, stream>>>(hB, wbfT + 3 * DIM * DIM, conv_b + 3 * DIM, hA, (const float*)nullptr, 0);

    // mean pool + head
    pool_kernel<<<(N_NODES + 255) / 256, 256, 0, stream>>>(hA, graph_id, gsum, gcnt, N_NODES);
    mlp_kernel<<<N_GRAPHS, 128, 0, stream>>>(gsum, gcnt, ffnn_W, ffnn_b, out_W, out_b, out);
}

// Round 8
// 399.385 us; speedup vs baseline: 1.0371x; 1.0315x over previous
//
#include <hip/hip_runtime.h>
#include <hip/hip_bf16.h>

#define N_NODES 50000
#define N_EDGES 600000
#define DIM 128
#define N_GRAPHS 64
#define CAP 64            // padded CSR row capacity (mean deg 12; P(deg>=64)~0)
#define CAP_SHIFT 6

typedef __bf16 bf16x8 __attribute__((ext_vector_type(8)));
typedef float f32x4 __attribute__((ext_vector_type(4)));
typedef float f32x2 __attribute__((ext_vector_type(2)));

// round-to-nearest-even fp32 -> bf16 (as ushort)
__device__ __forceinline__ unsigned short f2bf(float f) {
    unsigned int u = __float_as_uint(f);
    u += 0x7FFFu + ((u >> 16) & 1u);
    return (unsigned short)(u >> 16);
}
__device__ __forceinline__ float bflo(unsigned int u) {   // low bf16 of packed pair
    return __uint_as_float(u << 16);
}
__device__ __forceinline__ float bfhi(unsigned int u) {   // high bf16
    return __uint_as_float(u & 0xFFFF0000u);
}
// single fp32 -> fp8 e4m3 byte (hw packed convert, take low byte)
__device__ __forceinline__ unsigned char f2fp8(float v) {
    return (unsigned char)(__builtin_amdgcn_cvt_pk_fp8_f32(v, v, 0, false) & 0xFF);
}

// ---------------------------------------------------------------------------
// zero all accumulators in one launch
// ---------------------------------------------------------------------------
__global__ __launch_bounds__(256) void zero_kernel(int* __restrict__ deg_out,
                                                   int* __restrict__ cnt_in,
                                                   float* __restrict__ gsum,
                                                   float* __restrict__ gcnt) {
    int i = blockIdx.x * blockDim.x + threadIdx.x;
    if (i < N_NODES) { deg_out[i] = 0; cnt_in[i] = 0; }
    if (i < N_GRAPHS * DIM) gsum[i] = 0.f;
    if (i < N_GRAPHS) gcnt[i] = 0.f;
}

// ---------------------------------------------------------------------------
// fused CSR build: one pass over edges (int slots: 4B native scattered grain)
// ---------------------------------------------------------------------------
__global__ __launch_bounds__(256) void build_kernel(const int* __restrict__ src,
                                                    const int* __restrict__ dst,
                                                    int* __restrict__ deg_out,
                                                    int* __restrict__ cnt_in,
                                                    int* __restrict__ slots, int ne) {
    int e = blockIdx.x * blockDim.x + threadIdx.x;
    if (e < ne) {
        int s = src[e];
        int d = dst[e];
        atomicAdd(&deg_out[s], 1);
        int p = atomicAdd(&cnt_in[d], 1);
        if (p < CAP) slots[(d << CAP_SHIFT) + p] = s;
    }
}

// ---------------------------------------------------------------------------
// prep: norms + conv_W -> bf16 TRANSPOSED WT[l][n][k]
// ---------------------------------------------------------------------------
__global__ __launch_bounds__(256) void prep_kernel(const int* __restrict__ deg_out,
                                                   const int* __restrict__ deg_in,
                                                   float* __restrict__ norm_src,
                                                   float* __restrict__ norm_dst,
                                                   const float* __restrict__ w,
                                                   unsigned short* __restrict__ wt) {
    int i = blockIdx.x * blockDim.x + threadIdx.x;
    if (i < N_NODES) {
        norm_src[i] = 1.0f / sqrtf(fmaxf((float)deg_out[i], 1.0f));
        norm_dst[i] = 1.0f / sqrtf(fmaxf((float)deg_in[i], 1.0f));
    }
    if (i < 4 * DIM * DIM) {
        int l = i >> 14;           // layer
        int j = i & 16383;
        int k = j >> 7;
        int n = j & 127;
        wt[(l << 14) + n * DIM + k] = f2bf(w[i]);
    }
}

// ---------------------------------------------------------------------------
// xs(fp8) = e4m3( x * norm_src[row] )   (8 floats per thread -> 8 bytes)
// ---------------------------------------------------------------------------
__global__ __launch_bounds__(256) void scale_x_kernel(const float* __restrict__ x,
                                                      const float* __restrict__ norm_src,
                                                      unsigned char* __restrict__ xs) {
    int i = blockIdx.x * blockDim.x + threadIdx.x;     // 8-float chunk index
    if (i >= N_NODES * (DIM / 8)) return;
    int row = i >> 4;                                   // 16 chunks per row
    float ns = norm_src[row];
    const float4* px = (const float4*)(x + (size_t)i * 8);
    float4 v0 = px[0], v1 = px[1];
    unsigned lo = 0, hi = 0;
    lo = __builtin_amdgcn_cvt_pk_fp8_f32(v0.x * ns, v0.y * ns, lo, false);
    lo = __builtin_amdgcn_cvt_pk_fp8_f32(v0.z * ns, v0.w * ns, lo, true);
    hi = __builtin_amdgcn_cvt_pk_fp8_f32(v1.x * ns, v1.y * ns, hi, false);
    hi = __builtin_amdgcn_cvt_pk_fp8_f32(v1.z * ns, v1.w * ns, hi, true);
    uint2 o = {lo, hi};
    *(uint2*)(xs + (size_t)i * 8) = o;
}

// ---------------------------------------------------------------------------
// SpMM (fp8 h): out_bf16[d] = norm_dst[d] * sum_{s in in(d)} h8[s]
// wave = 4 edge-slots x 16 sub-lanes; sub covers 8 fp8 (8B); 2x unrolled
// fp8 row = 128B -> half the gather traffic of bf16
// ---------------------------------------------------------------------------
__global__ __launch_bounds__(256) void spmm_kernel(const int* __restrict__ cnt_in,
                                                   const int* __restrict__ slots,
                                                   const unsigned char* __restrict__ h8,
                                                   const float* __restrict__ norm_dst,
                                                   unsigned short* __restrict__ out) {
    int node = blockIdx.x * 4 + (threadIdx.x >> 6);
    if (node >= N_NODES) return;
    int lane = threadIdx.x & 63;
    int slot = lane >> 4;          // 0..3 : which edge in the group
    int sub  = lane & 15;          // fp8 chunk: bytes sub*8 .. sub*8+7
    int beg = node << CAP_SHIFT;
    int cnt = cnt_in[node];
    if (cnt > CAP) cnt = CAP;
    int end = beg + cnt;
    float a[8] = {}, b[8] = {};
    const unsigned char* hp = h8 + sub * 8;
    for (int base = beg; base < end; base += 8) {
        int e0 = base + slot;
        int e1 = e0 + 4;
        if (e0 < end) {
            uint2 v = *(const uint2*)(hp + (size_t)slots[e0] * DIM);
            f32x2 p0 = __builtin_amdgcn_cvt_pk_f32_fp8(v.x, false);
            f32x2 p1 = __builtin_amdgcn_cvt_pk_f32_fp8(v.x, true);
            f32x2 p2 = __builtin_amdgcn_cvt_pk_f32_fp8(v.y, false);
            f32x2 p3 = __builtin_amdgcn_cvt_pk_f32_fp8(v.y, true);
            a[0] += p0[0]; a[1] += p0[1]; a[2] += p1[0]; a[3] += p1[1];
            a[4] += p2[0]; a[5] += p2[1]; a[6] += p3[0]; a[7] += p3[1];
        }
        if (e1 < end) {
            uint2 v = *(const uint2*)(hp + (size_t)slots[e1] * DIM);
            f32x2 p0 = __builtin_amdgcn_cvt_pk_f32_fp8(v.x, false);
            f32x2 p1 = __builtin_amdgcn_cvt_pk_f32_fp8(v.x, true);
            f32x2 p2 = __builtin_amdgcn_cvt_pk_f32_fp8(v.y, false);
            f32x2 p3 = __builtin_amdgcn_cvt_pk_f32_fp8(v.y, true);
            b[0] += p0[0]; b[1] += p0[1]; b[2] += p1[0]; b[3] += p1[1];
            b[4] += p2[0]; b[5] += p2[1]; b[6] += p3[0]; b[7] += p3[1];
        }
    }
    #pragma unroll
    for (int j = 0; j < 8; j++) {
        a[j] += b[j];
        a[j] += __shfl_xor(a[j], 16);
        a[j] += __shfl_xor(a[j], 32);
    }
    if (slot == 0) {
        float nd = norm_dst[node];
        uint4 o;
        o.x = (unsigned)f2bf(a[0] * nd) | ((unsigned)f2bf(a[1] * nd) << 16);
        o.y = (unsigned)f2bf(a[2] * nd) | ((unsigned)f2bf(a[3] * nd) << 16);
        o.z = (unsigned)f2bf(a[4] * nd) | ((unsigned)f2bf(a[5] * nd) << 16);
        o.w = (unsigned)f2bf(a[6] * nd) | ((unsigned)f2bf(a[7] * nd) << 16);
        *(uint4*)(out + (size_t)node * DIM + sub * 8) = o;
    }
}

// ---------------------------------------------------------------------------
// GEMM via MFMA bf16: C = A[N,128] @ W[128,128] (+bias, relu, row_scale)
// A bf16, W bf16 transposed. Output: fp8 (C8, feeds next spmm) or bf16 (C16).
// ---------------------------------------------------------------------------
__global__ __launch_bounds__(256) void gemm_mfma_kernel(const unsigned short* __restrict__ A,
                                                        const unsigned short* __restrict__ WT,
                                                        const float* __restrict__ bias,
                                                        unsigned char* __restrict__ C8,
                                                        unsigned short* __restrict__ C16,
                                                        const float* __restrict__ row_scale,
                                                        int do_relu) {
    int wave = threadIdx.x >> 6;
    int lane = threadIdx.x & 63;
    int tile = blockIdx.x * 4 + wave;            // 0..3124
    if (tile >= N_NODES / 16) return;
    int r0 = tile * 16;
    int quad = lane >> 4;
    int l15 = lane & 15;

    f32x4 acc[8];
    #pragma unroll
    for (int ct = 0; ct < 8; ct++) {
        float bv = bias[ct * 16 + l15];
        acc[ct] = (f32x4){bv, bv, bv, bv};
    }

    #pragma unroll
    for (int ks = 0; ks < 4; ks++) {
        bf16x8 af = *(const bf16x8*)(A + (size_t)(r0 + l15) * DIM + ks * 32 + quad * 8);
        #pragma unroll
        for (int ct = 0; ct < 8; ct++) {
            bf16x8 bf = *(const bf16x8*)(WT + (size_t)(ct * 16 + l15) * DIM + ks * 32 + quad * 8);
            acc[ct] = __builtin_amdgcn_mfma_f32_16x16x32_bf16(af, bf, acc[ct], 0, 0, 0);
        }
    }

    #pragma unroll
    for (int ct = 0; ct < 8; ct++) {
        #pragma unroll
        for (int reg = 0; reg < 4; reg++) {
            int r = r0 + quad * 4 + reg;
            float v = acc[ct][reg];
            if (do_relu) v = fmaxf(v, 0.f);
            if (row_scale) v *= row_scale[r];
            if (C8) C8[(size_t)r * DIM + ct * 16 + l15] = f2fp8(v);
            else    C16[(size_t)r * DIM + ct * 16 + l15] = f2bf(v);
        }
    }
}

// ---------------------------------------------------------------------------
// mean-pool over bf16 h (graph_id sorted)
// ---------------------------------------------------------------------------
#define POOL_NPG 32
__global__ __launch_bounds__(256) void pool_kernel(const unsigned short* __restrict__ h,
                                                   const int* __restrict__ graph_id,
                                                   float* __restrict__ gsum,
                                                   float* __restrict__ gcnt, int n) {
    int group = threadIdx.x >> 5;
    int lane = threadIdx.x & 31;
    int base = (blockIdx.x * 8 + group) * POOL_NPG;
    if (base >= n) return;
    int end = base + POOL_NPG;
    if (end > n) end = n;
    float4 acc = {0.f, 0.f, 0.f, 0.f};
    int cur = graph_id[base];
    int cnt = 0;
    for (int i = base; i < end; i++) {
        int g = graph_id[i];
        if (g != cur) {
            float* p = gsum + cur * DIM + lane * 4;
            atomicAdd(p + 0, acc.x); atomicAdd(p + 1, acc.y);
            atomicAdd(p + 2, acc.z); atomicAdd(p + 3, acc.w);
            if (lane == 0) atomicAdd(&gcnt[cur], (float)cnt);
            acc = {0.f, 0.f, 0.f, 0.f}; cnt = 0; cur = g;
        }
        uint2 v = *(const uint2*)(h + (size_t)i * DIM + lane * 4);
        acc.x += bflo(v.x); acc.y += bfhi(v.x);
        acc.z += bflo(v.y); acc.w += bfhi(v.y);
        cnt++;
    }
    float* p = gsum + cur * DIM + lane * 4;
    atomicAdd(p + 0, acc.x); atomicAdd(p + 1, acc.y);
    atomicAdd(p + 2, acc.z); atomicAdd(p + 3, acc.w);
    if (lane == 0) atomicAdd(&gcnt[cur], (float)cnt);
}

// ---------------------------------------------------------------------------
// FFNN head: one block per graph (fp32)
// ---------------------------------------------------------------------------
__global__ __launch_bounds__(128) void mlp_kernel(const float* __restrict__ gsum,
                                                  const float* __restrict__ gcnt,
                                                  const float* __restrict__ ffnn_W,
                                                  const float* __restrict__ ffnn_b,
                                                  const float* __restrict__ out_W,
                                                  const float* __restrict__ out_b,
                                                  float* __restrict__ out) {
    __shared__ float buf[DIM];
    __shared__ float red[DIM];
    int g = blockIdx.x;
    int t = threadIdx.x;
    float cnt = fmaxf(gcnt[g], 1.0f);
    buf[t] = gsum[g * DIM + t] / cnt;
    __syncthreads();
    for (int l = 0; l < 3; l++) {
        const float* W = ffnn_W + (size_t)l * DIM * DIM;
        float s = ffnn_b[l * DIM + t];
        for (int k = 0; k < DIM; k++) s += buf[k] * W[k * DIM + t];
        __syncthreads();
        buf[t] = fmaxf(s, 0.0f);
        __syncthreads();
    }
    float p = buf[t] * out_W[t];
    red[t] = p;
    __syncthreads();
    for (int off = 64; off > 0; off >>= 1) {
        if (t < off) red[t] += red[t + off];
        __syncthreads();
    }
    if (t == 0) out[g] = 1.0f / (1.0f + expf(-(red[0] + out_b[0])));
}

// ---------------------------------------------------------------------------
// launch
// ---------------------------------------------------------------------------
extern "C" void kernel_launch(void* const* d_in, const int* in_sizes, int n_in,
                              void* d_out, int out_size, void* d_ws, size_t ws_size,
                              hipStream_t stream) {
    const float* x        = (const float*)d_in[0];
    const int*   src      = (const int*)d_in[1];
    const int*   dst      = (const int*)d_in[2];
    const int*   graph_id = (const int*)d_in[3];
    const float* conv_W   = (const float*)d_in[4];
    const float* conv_b   = (const float*)d_in[5];
    const float* ffnn_W   = (const float*)d_in[6];
    const float* ffnn_b   = (const float*)d_in[7];
    const float* out_W    = (const float*)d_in[8];
    const float* out_b    = (const float*)d_in[9];
    float* out = (float*)d_out;

    char* w = (char*)d_ws;
    auto alloc = [&](size_t bytes) -> void* {
        void* p = (void*)w;
        w += (bytes + 255) & ~(size_t)255;
        return p;
    };
    int*   deg_out_i = (int*)alloc(N_NODES * sizeof(int));
    int*   cnt_in    = (int*)alloc(N_NODES * sizeof(int));
    float* norm_src  = (float*)alloc(N_NODES * sizeof(float));
    float* norm_dst  = (float*)alloc(N_NODES * sizeof(float));
    int*   slots     = (int*)alloc((size_t)N_NODES * CAP * sizeof(int));
    unsigned char*  h8   = (unsigned char*)alloc((size_t)N_NODES * DIM);            // fp8 spmm input
    unsigned short* hB16 = (unsigned short*)alloc((size_t)N_NODES * DIM * 2);       // bf16 spmm output
    unsigned short* hP16 = (unsigned short*)alloc((size_t)N_NODES * DIM * 2);       // bf16 conv3 output
    unsigned short* wbfT = (unsigned short*)alloc(4 * DIM * DIM * sizeof(unsigned short));
    float* gsum      = (float*)alloc(N_GRAPHS * DIM * sizeof(float));
    float* gcnt      = (float*)alloc(N_GRAPHS * sizeof(float));

    zero_kernel<<<(N_NODES + 255) / 256, 256, 0, stream>>>(deg_out_i, cnt_in, gsum, gcnt);
    build_kernel<<<(N_EDGES + 255) / 256, 256, 0, stream>>>(src, dst, deg_out_i, cnt_in, slots, N_EDGES);
    prep_kernel<<<(4 * DIM * DIM + 255) / 256, 256, 0, stream>>>(deg_out_i, cnt_in, norm_src, norm_dst, conv_W, wbfT);
    scale_x_kernel<<<(N_NODES * (DIM / 8) + 255) / 256, 256, 0, stream>>>(x, norm_src, h8);

    const int spmm_blocks = (N_NODES + 3) / 4;
    const int gemm_blocks = (N_NODES / 16 + 3) / 4;   // 3125 tiles / 4 waves

    // conv0..2: spmm(h8 -> hB16); gemm(hB16 -> h8 fp8, relu, *norm_src)
    spmm_kernel<<<spmm_blocks, 256, 0, stream>>>(cnt_in, slots, h8, norm_dst, hB16);
    gemm_mfma_kernel<<<gemm_blocks, 256, 0, stream>>>(hB16, wbfT + 0 * DIM * DIM, conv_b + 0 * DIM, h8, (unsigned short*)nullptr, norm_src, 1);
    spmm_kernel<<<spmm_blocks, 256, 0, stream>>>(cnt_in, slots, h8, norm_dst, hB16);
    gemm_mfma_kernel<<<gemm_blocks, 256, 0, stream>>>(hB16, wbfT + 1 * DIM * DIM, conv_b + 1 * DIM, h8, (unsigned short*)nullptr, norm_src, 1);
    spmm_kernel<<<spmm_blocks, 256, 0, stream>>>(cnt_in, slots, h8, norm_dst, hB16);
    gemm_mfma_kernel<<<gemm_blocks, 256, 0, stream>>>(hB16, wbfT + 2 * DIM * DIM, conv_b + 2 * DIM, h8, (unsigned short*)nullptr, norm_src, 1);
    // conv3: spmm(h8 -> hB16); gemm(hB16 -> hP16 bf16, no relu, no scale)
    spmm_kernel<<<spmm_blocks, 256, 0, stream>>>(cnt_in, slots, h8, norm_dst, hB16);
    gemm_mfma_kernel<<<gemm_blocks, 256, 0, stream>>>(hB16, wbfT + 3 * DIM * DIM, conv_b + 3 * DIM, (unsigned char*)nullptr, hP16, (const float*)nullptr, 0);

    // mean pool + head
    pool_kernel<<<(N_NODES + 255) / 256, 256, 0, stream>>>(hP16, graph_id, gsum, gcnt, N_NODES);
    mlp_kernel<<<N_GRAPHS, 128, 0, stream>>>(gsum, gcnt, ffnn_W, ffnn_b, out_W, out_b, out);
}

// Round 9
// 353.676 us; speedup vs baseline: 1.1712x; 1.1292x over previous
//
#include <hip/hip_runtime.h>
#include <hip/hip_bf16.h>

#define N_NODES 50000
#define N_EDGES 600000
#define DIM 128
#define N_GRAPHS 64
#define CAP 64            // padded CSR row capacity (mean deg 12; P(deg>=64)~0)
#define CAP_SHIFT 6

typedef __bf16 bf16x8 __attribute__((ext_vector_type(8)));
typedef float f32x4 __attribute__((ext_vector_type(4)));
typedef float f32x2 __attribute__((ext_vector_type(2)));

// round-to-nearest-even fp32 -> bf16 (as ushort)
__device__ __forceinline__ unsigned short f2bf(float f) {
    unsigned int u = __float_as_uint(f);
    u += 0x7FFFu + ((u >> 16) & 1u);
    return (unsigned short)(u >> 16);
}
__device__ __forceinline__ float bflo(unsigned int u) {   // low bf16 of packed pair
    return __uint_as_float(u << 16);
}
__device__ __forceinline__ float bfhi(unsigned int u) {   // high bf16
    return __uint_as_float(u & 0xFFFF0000u);
}
__device__ __forceinline__ unsigned char f2fp8(float v) {
    return (unsigned char)(__builtin_amdgcn_cvt_pk_fp8_f32(v, v, 0, false) & 0xFF);
}

// ---------------------------------------------------------------------------
// zero all accumulators in one launch
// ---------------------------------------------------------------------------
__global__ __launch_bounds__(256) void zero_kernel(int* __restrict__ deg_out,
                                                   int* __restrict__ cnt_in,
                                                   float* __restrict__ gsum,
                                                   float* __restrict__ gcnt) {
    int i = blockIdx.x * blockDim.x + threadIdx.x;
    if (i < N_NODES) { deg_out[i] = 0; cnt_in[i] = 0; }
    if (i < N_GRAPHS * DIM) gsum[i] = 0.f;
    if (i < N_GRAPHS) gcnt[i] = 0.f;
}

// ---------------------------------------------------------------------------
// fused CSR build: one pass over edges (int slots: 4B native scattered grain)
// ---------------------------------------------------------------------------
__global__ __launch_bounds__(256) void build_kernel(const int* __restrict__ src,
                                                    const int* __restrict__ dst,
                                                    int* __restrict__ deg_out,
                                                    int* __restrict__ cnt_in,
                                                    int* __restrict__ slots, int ne) {
    int e = blockIdx.x * blockDim.x + threadIdx.x;
    if (e < ne) {
        int s = src[e];
        int d = dst[e];
        atomicAdd(&deg_out[s], 1);
        int p = atomicAdd(&cnt_in[d], 1);
        if (p < CAP) slots[(d << CAP_SHIFT) + p] = s;
    }
}

// ---------------------------------------------------------------------------
// prep: norms + conv_W -> bf16 TRANSPOSED WT[l][n][k]
// ---------------------------------------------------------------------------
__global__ __launch_bounds__(256) void prep_kernel(const int* __restrict__ deg_out,
                                                   const int* __restrict__ deg_in,
                                                   float* __restrict__ norm_src,
                                                   float* __restrict__ norm_dst,
                                                   const float* __restrict__ w,
                                                   unsigned short* __restrict__ wt) {
    int i = blockIdx.x * blockDim.x + threadIdx.x;
    if (i < N_NODES) {
        norm_src[i] = 1.0f / sqrtf(fmaxf((float)deg_out[i], 1.0f));
        norm_dst[i] = 1.0f / sqrtf(fmaxf((float)deg_in[i], 1.0f));
    }
    if (i < 4 * DIM * DIM) {
        int l = i >> 14;           // layer
        int j = i & 16383;
        int k = j >> 7;
        int n = j & 127;
        wt[(l << 14) + n * DIM + k] = f2bf(w[i]);
    }
}

// ---------------------------------------------------------------------------
// xs(fp8) = e4m3( x * norm_src[row] )
// ---------------------------------------------------------------------------
__global__ __launch_bounds__(256) void scale_x_kernel(const float* __restrict__ x,
                                                      const float* __restrict__ norm_src,
                                                      unsigned char* __restrict__ xs) {
    int i = blockIdx.x * blockDim.x + threadIdx.x;     // 8-float chunk index
    if (i >= N_NODES * (DIM / 8)) return;
    int row = i >> 4;                                   // 16 chunks per row
    float ns = norm_src[row];
    const float4* px = (const float4*)(x + (size_t)i * 8);
    float4 v0 = px[0], v1 = px[1];
    unsigned lo = 0, hi = 0;
    lo = __builtin_amdgcn_cvt_pk_fp8_f32(v0.x * ns, v0.y * ns, lo, false);
    lo = __builtin_amdgcn_cvt_pk_fp8_f32(v0.z * ns, v0.w * ns, lo, true);
    hi = __builtin_amdgcn_cvt_pk_fp8_f32(v1.x * ns, v1.y * ns, hi, false);
    hi = __builtin_amdgcn_cvt_pk_fp8_f32(v1.z * ns, v1.w * ns, hi, true);
    uint2 o = {lo, hi};
    *(uint2*)(xs + (size_t)i * 8) = o;
}

// ---------------------------------------------------------------------------
// FUSED conv: per block (256 thr = 4 waves) handle 16 nodes.
// Phase 1 (spmm): wave w aggregates nodes [blk*16+4w .. +3] from fp8 h8
//   (4 edge-slots x 16 sub-lanes, 8 edges in flight), scales by norm_dst,
//   stores bf16 rows into LDS (row stride 272B -> 2-way bank alias = free).
// Phase 2 (gemm): wave w computes C[16 x cols 32w..32w+31] = LDS_A @ WT
//   via 8 x mfma_f32_16x16x32_bf16; epilogue relu/row_scale; out fp8 or bf16.
// ---------------------------------------------------------------------------
#define LDS_STRIDE 136   // ushorts per row (128 + 8 pad = 272B)
__global__ __launch_bounds__(256) void conv_fused_kernel(const int* __restrict__ cnt_in,
                                                         const int* __restrict__ slots,
                                                         const unsigned char* __restrict__ h8,
                                                         const float* __restrict__ norm_dst,
                                                         const unsigned short* __restrict__ WT,
                                                         const float* __restrict__ bias,
                                                         unsigned char* __restrict__ C8,
                                                         unsigned short* __restrict__ C16,
                                                         const float* __restrict__ row_scale,
                                                         int do_relu) {
    __shared__ unsigned short tileA[16][LDS_STRIDE];
    int wave = threadIdx.x >> 6;
    int lane = threadIdx.x & 63;
    int slot = lane >> 4;          // 0..3
    int sub  = lane & 15;          // 8-byte chunk of the 128-byte fp8 row
    int r0 = blockIdx.x * 16;

    // ---- phase 1: aggregate 4 nodes per wave ----
    const unsigned char* hp = h8 + sub * 8;
    for (int nn = 0; nn < 4; nn++) {
        int lrow = wave * 4 + nn;
        int node = r0 + lrow;
        int beg = node << CAP_SHIFT;
        int cnt = cnt_in[node];
        if (cnt > CAP) cnt = CAP;
        int end = beg + cnt;
        float a[8] = {}, b[8] = {};
        for (int base = beg; base < end; base += 8) {
            int e0 = base + slot;
            int e1 = e0 + 4;
            if (e0 < end) {
                uint2 v = *(const uint2*)(hp + (size_t)slots[e0] * DIM);
                f32x2 p0 = __builtin_amdgcn_cvt_pk_f32_fp8(v.x, false);
                f32x2 p1 = __builtin_amdgcn_cvt_pk_f32_fp8(v.x, true);
                f32x2 p2 = __builtin_amdgcn_cvt_pk_f32_fp8(v.y, false);
                f32x2 p3 = __builtin_amdgcn_cvt_pk_f32_fp8(v.y, true);
                a[0] += p0[0]; a[1] += p0[1]; a[2] += p1[0]; a[3] += p1[1];
                a[4] += p2[0]; a[5] += p2[1]; a[6] += p3[0]; a[7] += p3[1];
            }
            if (e1 < end) {
                uint2 v = *(const uint2*)(hp + (size_t)slots[e1] * DIM);
                f32x2 p0 = __builtin_amdgcn_cvt_pk_f32_fp8(v.x, false);
                f32x2 p1 = __builtin_amdgcn_cvt_pk_f32_fp8(v.x, true);
                f32x2 p2 = __builtin_amdgcn_cvt_pk_f32_fp8(v.y, false);
                f32x2 p3 = __builtin_amdgcn_cvt_pk_f32_fp8(v.y, true);
                b[0] += p0[0]; b[1] += p0[1]; b[2] += p1[0]; b[3] += p1[1];
                b[4] += p2[0]; b[5] += p2[1]; b[6] += p3[0]; b[7] += p3[1];
            }
        }
        #pragma unroll
        for (int j = 0; j < 8; j++) {
            a[j] += b[j];
            a[j] += __shfl_xor(a[j], 16);
            a[j] += __shfl_xor(a[j], 32);
        }
        if (slot == 0) {
            float nd = norm_dst[node];
            uint4 o;
            o.x = (unsigned)f2bf(a[0] * nd) | ((unsigned)f2bf(a[1] * nd) << 16);
            o.y = (unsigned)f2bf(a[2] * nd) | ((unsigned)f2bf(a[3] * nd) << 16);
            o.z = (unsigned)f2bf(a[4] * nd) | ((unsigned)f2bf(a[5] * nd) << 16);
            o.w = (unsigned)f2bf(a[6] * nd) | ((unsigned)f2bf(a[7] * nd) << 16);
            *(uint4*)&tileA[lrow][sub * 8] = o;
        }
    }
    __syncthreads();

    // ---- phase 2: C[16 x 32-col slice] via MFMA ----
    int quad = lane >> 4;
    int l15 = lane & 15;
    int ct0 = wave * 2;            // two 16-col tiles per wave

    f32x4 acc[2];
    #pragma unroll
    for (int t = 0; t < 2; t++) {
        float bv = bias[(ct0 + t) * 16 + l15];
        acc[t] = (f32x4){bv, bv, bv, bv};
    }

    #pragma unroll
    for (int ks = 0; ks < 4; ks++) {
        bf16x8 af = *(const bf16x8*)&tileA[l15][ks * 32 + quad * 8];
        #pragma unroll
        for (int t = 0; t < 2; t++) {
            bf16x8 bf = *(const bf16x8*)(WT + (size_t)((ct0 + t) * 16 + l15) * DIM + ks * 32 + quad * 8);
            acc[t] = __builtin_amdgcn_mfma_f32_16x16x32_bf16(af, bf, acc[t], 0, 0, 0);
        }
    }

    #pragma unroll
    for (int t = 0; t < 2; t++) {
        #pragma unroll
        for (int reg = 0; reg < 4; reg++) {
            int r = r0 + quad * 4 + reg;
            float v = acc[t][reg];
            if (do_relu) v = fmaxf(v, 0.f);
            if (row_scale) v *= row_scale[r];
            if (C8) C8[(size_t)r * DIM + (ct0 + t) * 16 + l15] = f2fp8(v);
            else    C16[(size_t)r * DIM + (ct0 + t) * 16 + l15] = f2bf(v);
        }
    }
}

// ---------------------------------------------------------------------------
// mean-pool over bf16 h (graph_id sorted)
// ---------------------------------------------------------------------------
#define POOL_NPG 32
__global__ __launch_bounds__(256) void pool_kernel(const unsigned short* __restrict__ h,
                                                   const int* __restrict__ graph_id,
                                                   float* __restrict__ gsum,
                                                   float* __restrict__ gcnt, int n) {
    int group = threadIdx.x >> 5;
    int lane = threadIdx.x & 31;
    int base = (blockIdx.x * 8 + group) * POOL_NPG;
    if (base >= n) return;
    int end = base + POOL_NPG;
    if (end > n) end = n;
    float4 acc = {0.f, 0.f, 0.f, 0.f};
    int cur = graph_id[base];
    int cnt = 0;
    for (int i = base; i < end; i++) {
        int g = graph_id[i];
        if (g != cur) {
            float* p = gsum + cur * DIM + lane * 4;
            atomicAdd(p + 0, acc.x); atomicAdd(p + 1, acc.y);
            atomicAdd(p + 2, acc.z); atomicAdd(p + 3, acc.w);
            if (lane == 0) atomicAdd(&gcnt[cur], (float)cnt);
            acc = {0.f, 0.f, 0.f, 0.f}; cnt = 0; cur = g;
        }
        uint2 v = *(const uint2*)(h + (size_t)i * DIM + lane * 4);
        acc.x += bflo(v.x); acc.y += bfhi(v.x);
        acc.z += bflo(v.y); acc.w += bfhi(v.y);
        cnt++;
    }
    float* p = gsum + cur * DIM + lane * 4;
    atomicAdd(p + 0, acc.x); atomicAdd(p + 1, acc.y);
    atomicAdd(p + 2, acc.z); atomicAdd(p + 3, acc.w);
    if (lane == 0) atomicAdd(&gcnt[cur], (float)cnt);
}

// ---------------------------------------------------------------------------
// FFNN head: one block per graph (fp32)
// ---------------------------------------------------------------------------
__global__ __launch_bounds__(128) void mlp_kernel(const float* __restrict__ gsum,
                                                  const float* __restrict__ gcnt,
                                                  const float* __restrict__ ffnn_W,
                                                  const float* __restrict__ ffnn_b,
                                                  const float* __restrict__ out_W,
                                                  const float* __restrict__ out_b,
                                                  float* __restrict__ out) {
    __shared__ float buf[DIM];
    __shared__ float red[DIM];
    int g = blockIdx.x;
    int t = threadIdx.x;
    float cnt = fmaxf(gcnt[g], 1.0f);
    buf[t] = gsum[g * DIM + t] / cnt;
    __syncthreads();
    for (int l = 0; l < 3; l++) {
        const float* W = ffnn_W + (size_t)l * DIM * DIM;
        float s = ffnn_b[l * DIM + t];
        for (int k = 0; k < DIM; k++) s += buf[k] * W[k * DIM + t];
        __syncthreads();
        buf[t] = fmaxf(s, 0.0f);
        __syncthreads();
    }
    float p = buf[t] * out_W[t];
    red[t] = p;
    __syncthreads();
    for (int off = 64; off > 0; off >>= 1) {
        if (t < off) red[t] += red[t + off];
        __syncthreads();
    }
    if (t == 0) out[g] = 1.0f / (1.0f + expf(-(red[0] + out_b[0])));
}

// ---------------------------------------------------------------------------
// launch
// ---------------------------------------------------------------------------
extern "C" void kernel_launch(void* const* d_in, const int* in_sizes, int n_in,
                              void* d_out, int out_size, void* d_ws, size_t ws_size,
                              hipStream_t stream) {
    const float* x        = (const float*)d_in[0];
    const int*   src      = (const int*)d_in[1];
    const int*   dst      = (const int*)d_in[2];
    const int*   graph_id = (const int*)d_in[3];
    const float* conv_W   = (const float*)d_in[4];
    const float* conv_b   = (const float*)d_in[5];
    const float* ffnn_W   = (const float*)d_in[6];
    const float* ffnn_b   = (const float*)d_in[7];
    const float* out_W    = (const float*)d_in[8];
    const float* out_b    = (const float*)d_in[9];
    float* out = (float*)d_out;

    char* w = (char*)d_ws;
    auto alloc = [&](size_t bytes) -> void* {
        void* p = (void*)w;
        w += (bytes + 255) & ~(size_t)255;
        return p;
    };
    int*   deg_out_i = (int*)alloc(N_NODES * sizeof(int));
    int*   cnt_in    = (int*)alloc(N_NODES * sizeof(int));
    float* norm_src  = (float*)alloc(N_NODES * sizeof(float));
    float* norm_dst  = (float*)alloc(N_NODES * sizeof(float));
    int*   slots     = (int*)alloc((size_t)N_NODES * CAP * sizeof(int));
    unsigned char*  h8a  = (unsigned char*)alloc((size_t)N_NODES * DIM);          // fp8 ping
    unsigned char*  h8b  = (unsigned char*)alloc((size_t)N_NODES * DIM);          // fp8 pong
    unsigned short* hP16 = (unsigned short*)alloc((size_t)N_NODES * DIM * 2);     // bf16 conv3 output
    unsigned short* wbfT = (unsigned short*)alloc(4 * DIM * DIM * sizeof(unsigned short));
    float* gsum      = (float*)alloc(N_GRAPHS * DIM * sizeof(float));
    float* gcnt      = (float*)alloc(N_GRAPHS * sizeof(float));

    zero_kernel<<<(N_NODES + 255) / 256, 256, 0, stream>>>(deg_out_i, cnt_in, gsum, gcnt);
    build_kernel<<<(N_EDGES + 255) / 256, 256, 0, stream>>>(src, dst, deg_out_i, cnt_in, slots, N_EDGES);
    prep_kernel<<<(4 * DIM * DIM + 255) / 256, 256, 0, stream>>>(deg_out_i, cnt_in, norm_src, norm_dst, conv_W, wbfT);
    scale_x_kernel<<<(N_NODES * (DIM / 8) + 255) / 256, 256, 0, stream>>>(x, norm_src, h8a);

    const int conv_blocks = N_NODES / 16;   // 3125

    // conv0..2: fused spmm+gemm, fp8 out (relu, *norm_src)
    conv_fused_kernel<<<conv_blocks, 256, 0, stream>>>(cnt_in, slots, h8a, norm_dst,
        wbfT + 0 * DIM * DIM, conv_b + 0 * DIM, h8b, (unsigned short*)nullptr, norm_src, 1);
    conv_fused_kernel<<<conv_blocks, 256, 0, stream>>>(cnt_in, slots, h8b, norm_dst,
        wbfT + 1 * DIM * DIM, conv_b + 1 * DIM, h8a, (unsigned short*)nullptr, norm_src, 1);
    conv_fused_kernel<<<conv_blocks, 256, 0, stream>>>(cnt_in, slots, h8a, norm_dst,
        wbfT + 2 * DIM * DIM, conv_b + 2 * DIM, h8b, (unsigned short*)nullptr, norm_src, 1);
    // conv3: bf16 out, no relu, no scale
    conv_fused_kernel<<<conv_blocks, 256, 0, stream>>>(cnt_in, slots, h8b, norm_dst,
        wbfT + 3 * DIM * DIM, conv_b + 3 * DIM, (unsigned char*)nullptr, hP16, (const float*)nullptr, 0);

    // mean pool + head
    pool_kernel<<<(N_NODES + 255) / 256, 256, 0, stream>>>(hP16, graph_id, gsum, gcnt, N_NODES);
    mlp_kernel<<<N_GRAPHS, 128, 0, stream>>>(gsum, gcnt, ffnn_W, ffnn_b, out_W, out_b, out);
}

// Round 10
// 333.816 us; speedup vs baseline: 1.2408x; 1.0595x over previous
//
#include <hip/hip_runtime.h>
#include <hip/hip_bf16.h>

#define N_NODES 50000
#define N_EDGES 600000
#define DIM 128
#define N_GRAPHS 64
#define CAP 64            // padded CSR row capacity (mean deg 12; P(deg>=64)~0)
#define CAP_SHIFT 6

typedef __bf16 bf16x8 __attribute__((ext_vector_type(8)));
typedef float f32x4 __attribute__((ext_vector_type(4)));
typedef float f32x2 __attribute__((ext_vector_type(2)));

// round-to-nearest-even fp32 -> bf16 (as ushort)
__device__ __forceinline__ unsigned short f2bf(float f) {
    unsigned int u = __float_as_uint(f);
    u += 0x7FFFu + ((u >> 16) & 1u);
    return (unsigned short)(u >> 16);
}
__device__ __forceinline__ float bflo(unsigned int u) {   // low bf16 of packed pair
    return __uint_as_float(u << 16);
}
__device__ __forceinline__ float bfhi(unsigned int u) {   // high bf16
    return __uint_as_float(u & 0xFFFF0000u);
}
__device__ __forceinline__ unsigned char f2fp8(float v) {
    return (unsigned char)(__builtin_amdgcn_cvt_pk_fp8_f32(v, v, 0, false) & 0xFF);
}

// ---------------------------------------------------------------------------
// zero all accumulators in one launch
// ---------------------------------------------------------------------------
__global__ __launch_bounds__(256) void zero_kernel(int* __restrict__ deg_out,
                                                   int* __restrict__ cnt_in,
                                                   float* __restrict__ gsum,
                                                   float* __restrict__ gcnt) {
    int i = blockIdx.x * blockDim.x + threadIdx.x;
    if (i < N_NODES) { deg_out[i] = 0; cnt_in[i] = 0; }
    if (i < N_GRAPHS * DIM) gsum[i] = 0.f;
    if (i < N_GRAPHS) gcnt[i] = 0.f;
}

// ---------------------------------------------------------------------------
// fused CSR build: one pass over edges (int slots: 4B native scattered grain)
// ---------------------------------------------------------------------------
__global__ __launch_bounds__(256) void build_kernel(const int* __restrict__ src,
                                                    const int* __restrict__ dst,
                                                    int* __restrict__ deg_out,
                                                    int* __restrict__ cnt_in,
                                                    int* __restrict__ slots, int ne) {
    int e = blockIdx.x * blockDim.x + threadIdx.x;
    if (e < ne) {
        int s = src[e];
        int d = dst[e];
        atomicAdd(&deg_out[s], 1);
        int p = atomicAdd(&cnt_in[d], 1);
        if (p < CAP) slots[(d << CAP_SHIFT) + p] = s;
    }
}

// ---------------------------------------------------------------------------
// prep: norms + conv_W -> bf16 TRANSPOSED WT[l][n][k]
// ---------------------------------------------------------------------------
__global__ __launch_bounds__(256) void prep_kernel(const int* __restrict__ deg_out,
                                                   const int* __restrict__ deg_in,
                                                   float* __restrict__ norm_src,
                                                   float* __restrict__ norm_dst,
                                                   const float* __restrict__ w,
                                                   unsigned short* __restrict__ wt) {
    int i = blockIdx.x * blockDim.x + threadIdx.x;
    if (i < N_NODES) {
        norm_src[i] = 1.0f / sqrtf(fmaxf((float)deg_out[i], 1.0f));
        norm_dst[i] = 1.0f / sqrtf(fmaxf((float)deg_in[i], 1.0f));
    }
    if (i < 4 * DIM * DIM) {
        int l = i >> 14;           // layer
        int j = i & 16383;
        int k = j >> 7;
        int n = j & 127;
        wt[(l << 14) + n * DIM + k] = f2bf(w[i]);
    }
}

// ---------------------------------------------------------------------------
// xs(fp8) = e4m3( x * norm_src[row] )
// ---------------------------------------------------------------------------
__global__ __launch_bounds__(256) void scale_x_kernel(const float* __restrict__ x,
                                                      const float* __restrict__ norm_src,
                                                      unsigned char* __restrict__ xs) {
    int i = blockIdx.x * blockDim.x + threadIdx.x;     // 8-float chunk index
    if (i >= N_NODES * (DIM / 8)) return;
    int row = i >> 4;                                   // 16 chunks per row
    float ns = norm_src[row];
    const float4* px = (const float4*)(x + (size_t)i * 8);
    float4 v0 = px[0], v1 = px[1];
    unsigned lo = 0, hi = 0;
    lo = __builtin_amdgcn_cvt_pk_fp8_f32(v0.x * ns, v0.y * ns, lo, false);
    lo = __builtin_amdgcn_cvt_pk_fp8_f32(v0.z * ns, v0.w * ns, lo, true);
    hi = __builtin_amdgcn_cvt_pk_fp8_f32(v1.x * ns, v1.y * ns, hi, false);
    hi = __builtin_amdgcn_cvt_pk_fp8_f32(v1.z * ns, v1.w * ns, hi, true);
    uint2 o = {lo, hi};
    *(uint2*)(xs + (size_t)i * 8) = o;
}

// ---------------------------------------------------------------------------
// FUSED conv: per block (256 thr = 4 waves) handle 16 nodes.
// Phase 1 (spmm): wave w aggregates nodes [blk*16+4w .. +3] from fp8 h8.
//   Index prefetch: lane sub loads slots[beg+base+sub] (one vector load per
//   16-edge chunk), distributed via __shfl -> each lane issues its 4 row
//   loads with no index dependency (16 rows in flight per wave).
// Phase 2 (gemm): wave w computes C[16 x cols 32w..32w+31] = LDS_A @ WT
//   via 8 x mfma_f32_16x16x32_bf16; epilogue relu/row_scale; out fp8 or bf16.
// ---------------------------------------------------------------------------
#define LDS_STRIDE 136   // ushorts per row (128 + 8 pad = 272B)
__global__ __launch_bounds__(256) void conv_fused_kernel(const int* __restrict__ cnt_in,
                                                         const int* __restrict__ slots,
                                                         const unsigned char* __restrict__ h8,
                                                         const float* __restrict__ norm_dst,
                                                         const unsigned short* __restrict__ WT,
                                                         const float* __restrict__ bias,
                                                         unsigned char* __restrict__ C8,
                                                         unsigned short* __restrict__ C16,
                                                         const float* __restrict__ row_scale,
                                                         int do_relu) {
    __shared__ unsigned short tileA[16][LDS_STRIDE];
    int wave = threadIdx.x >> 6;
    int lane = threadIdx.x & 63;
    int slot = lane >> 4;          // 0..3
    int sub  = lane & 15;          // 8-byte chunk of the 128-byte fp8 row
    int r0 = blockIdx.x * 16;

    // ---- phase 1: aggregate 4 nodes per wave ----
    const unsigned char* hp = h8 + sub * 8;
    #pragma unroll
    for (int nn = 0; nn < 4; nn++) {
        int lrow = wave * 4 + nn;
        int node = r0 + lrow;
        int beg = node << CAP_SHIFT;
        int cnt = cnt_in[node];
        if (cnt > CAP) cnt = CAP;
        float a[8] = {};
        for (int base = 0; base < cnt; base += 16) {
            // one vector load covers 16 edge indices (lanes with same sub broadcast)
            int idx = slots[beg + base + sub];     // valid iff base+sub < cnt (else reads pad, unused)
            #pragma unroll
            for (int j = 0; j < 4; j++) {
                int e = base + slot + 4 * j;
                int s = __shfl(idx, slot + 4 * j); // index from lane (slot+4j)
                if (e < cnt) {
                    uint2 v = *(const uint2*)(hp + (size_t)s * DIM);
                    f32x2 p0 = __builtin_amdgcn_cvt_pk_f32_fp8(v.x, false);
                    f32x2 p1 = __builtin_amdgcn_cvt_pk_f32_fp8(v.x, true);
                    f32x2 p2 = __builtin_amdgcn_cvt_pk_f32_fp8(v.y, false);
                    f32x2 p3 = __builtin_amdgcn_cvt_pk_f32_fp8(v.y, true);
                    a[0] += p0[0]; a[1] += p0[1]; a[2] += p1[0]; a[3] += p1[1];
                    a[4] += p2[0]; a[5] += p2[1]; a[6] += p3[0]; a[7] += p3[1];
                }
            }
        }
        #pragma unroll
        for (int j = 0; j < 8; j++) {
            a[j] += __shfl_xor(a[j], 16);
            a[j] += __shfl_xor(a[j], 32);
        }
        if (slot == 0) {
            float nd = norm_dst[node];
            uint4 o;
            o.x = (unsigned)f2bf(a[0] * nd) | ((unsigned)f2bf(a[1] * nd) << 16);
            o.y = (unsigned)f2bf(a[2] * nd) | ((unsigned)f2bf(a[3] * nd) << 16);
            o.z = (unsigned)f2bf(a[4] * nd) | ((unsigned)f2bf(a[5] * nd) << 16);
            o.w = (unsigned)f2bf(a[6] * nd) | ((unsigned)f2bf(a[7] * nd) << 16);
            *(uint4*)&tileA[lrow][sub * 8] = o;
        }
    }
    __syncthreads();

    // ---- phase 2: C[16 x 32-col slice] via MFMA ----
    int quad = lane >> 4;
    int l15 = lane & 15;
    int ct0 = wave * 2;            // two 16-col tiles per wave

    f32x4 acc[2];
    #pragma unroll
    for (int t = 0; t < 2; t++) {
        float bv = bias[(ct0 + t) * 16 + l15];
        acc[t] = (f32x4){bv, bv, bv, bv};
    }

    #pragma unroll
    for (int ks = 0; ks < 4; ks++) {
        bf16x8 af = *(const bf16x8*)&tileA[l15][ks * 32 + quad * 8];
        #pragma unroll
        for (int t = 0; t < 2; t++) {
            bf16x8 bf = *(const bf16x8*)(WT + (size_t)((ct0 + t) * 16 + l15) * DIM + ks * 32 + quad * 8);
            acc[t] = __builtin_amdgcn_mfma_f32_16x16x32_bf16(af, bf, acc[t], 0, 0, 0);
        }
    }

    #pragma unroll
    for (int t = 0; t < 2; t++) {
        #pragma unroll
        for (int reg = 0; reg < 4; reg++) {
            int r = r0 + quad * 4 + reg;
            float v = acc[t][reg];
            if (do_relu) v = fmaxf(v, 0.f);
            if (row_scale) v *= row_scale[r];
            if (C8) C8[(size_t)r * DIM + (ct0 + t) * 16 + l15] = f2fp8(v);
            else    C16[(size_t)r * DIM + (ct0 + t) * 16 + l15] = f2bf(v);
        }
    }
}

// ---------------------------------------------------------------------------
// mean-pool over bf16 h (graph_id sorted)
// ---------------------------------------------------------------------------
#define POOL_NPG 32
__global__ __launch_bounds__(256) void pool_kernel(const unsigned short* __restrict__ h,
                                                   const int* __restrict__ graph_id,
                                                   float* __restrict__ gsum,
                                                   float* __restrict__ gcnt, int n) {
    int group = threadIdx.x >> 5;
    int lane = threadIdx.x & 31;
    int base = (blockIdx.x * 8 + group) * POOL_NPG;
    if (base >= n) return;
    int end = base + POOL_NPG;
    if (end > n) end = n;
    float4 acc = {0.f, 0.f, 0.f, 0.f};
    int cur = graph_id[base];
    int cnt = 0;
    for (int i = base; i < end; i++) {
        int g = graph_id[i];
        if (g != cur) {
            float* p = gsum + cur * DIM + lane * 4;
            atomicAdd(p + 0, acc.x); atomicAdd(p + 1, acc.y);
            atomicAdd(p + 2, acc.z); atomicAdd(p + 3, acc.w);
            if (lane == 0) atomicAdd(&gcnt[cur], (float)cnt);
            acc = {0.f, 0.f, 0.f, 0.f}; cnt = 0; cur = g;
        }
        uint2 v = *(const uint2*)(h + (size_t)i * DIM + lane * 4);
        acc.x += bflo(v.x); acc.y += bfhi(v.x);
        acc.z += bflo(v.y); acc.w += bfhi(v.y);
        cnt++;
    }
    float* p = gsum + cur * DIM + lane * 4;
    atomicAdd(p + 0, acc.x); atomicAdd(p + 1, acc.y);
    atomicAdd(p + 2, acc.z); atomicAdd(p + 3, acc.w);
    if (lane == 0) atomicAdd(&gcnt[cur], (float)cnt);
}

// ---------------------------------------------------------------------------
// FFNN head: one block per graph (fp32)
// ---------------------------------------------------------------------------
__global__ __launch_bounds__(128) void mlp_kernel(const float* __restrict__ gsum,
                                                  const float* __restrict__ gcnt,
                                                  const float* __restrict__ ffnn_W,
                                                  const float* __restrict__ ffnn_b,
                                                  const float* __restrict__ out_W,
                                                  const float* __restrict__ out_b,
                                                  float* __restrict__ out) {
    __shared__ float buf[DIM];
    __shared__ float red[DIM];
    int g = blockIdx.x;
    int t = threadIdx.x;
    float cnt = fmaxf(gcnt[g], 1.0f);
    buf[t] = gsum[g * DIM + t] / cnt;
    __syncthreads();
    for (int l = 0; l < 3; l++) {
        const float* W = ffnn_W + (size_t)l * DIM * DIM;
        float s = ffnn_b[l * DIM + t];
        for (int k = 0; k < DIM; k++) s += buf[k] * W[k * DIM + t];
        __syncthreads();
        buf[t] = fmaxf(s, 0.0f);
        __syncthreads();
    }
    float p = buf[t] * out_W[t];
    red[t] = p;
    __syncthreads();
    for (int off = 64; off > 0; off >>= 1) {
        if (t < off) red[t] += red[t + off];
        __syncthreads();
    }
    if (t == 0) out[g] = 1.0f / (1.0f + expf(-(red[0] + out_b[0])));
}

// ---------------------------------------------------------------------------
// launch
// ---------------------------------------------------------------------------
extern "C" void kernel_launch(void* const* d_in, const int* in_sizes, int n_in,
                              void* d_out, int out_size, void* d_ws, size_t ws_size,
                              hipStream_t stream) {
    const float* x        = (const float*)d_in[0];
    const int*   src      = (const int*)d_in[1];
    const int*   dst      = (const int*)d_in[2];
    const int*   graph_id = (const int*)d_in[3];
    const float* conv_W   = (const float*)d_in[4];
    const float* conv_b   = (const float*)d_in[5];
    const float* ffnn_W   = (const float*)d_in[6];
    const float* ffnn_b   = (const float*)d_in[7];
    const float* out_W    = (const float*)d_in[8];
    const float* out_b    = (const float*)d_in[9];
    float* out = (float*)d_out;

    char* w = (char*)d_ws;
    auto alloc = [&](size_t bytes) -> void* {
        void* p = (void*)w;
        w += (bytes + 255) & ~(size_t)255;
        return p;
    };
    int*   deg_out_i = (int*)alloc(N_NODES * sizeof(int));
    int*   cnt_in    = (int*)alloc(N_NODES * sizeof(int));
    float* norm_src  = (float*)alloc(N_NODES * sizeof(float));
    float* norm_dst  = (float*)alloc(N_NODES * sizeof(float));
    int*   slots     = (int*)alloc((size_t)N_NODES * CAP * sizeof(int));
    unsigned char*  h8a  = (unsigned char*)alloc((size_t)N_NODES * DIM);          // fp8 ping
    unsigned char*  h8b  = (unsigned char*)alloc((size_t)N_NODES * DIM);          // fp8 pong
    unsigned short* hP16 = (unsigned short*)alloc((size_t)N_NODES * DIM * 2);     // bf16 conv3 output
    unsigned short* wbfT = (unsigned short*)alloc(4 * DIM * DIM * sizeof(unsigned short));
    float* gsum      = (float*)alloc(N_GRAPHS * DIM * sizeof(float));
    float* gcnt      = (float*)alloc(N_GRAPHS * sizeof(float));

    zero_kernel<<<(N_NODES + 255) / 256, 256, 0, stream>>>(deg_out_i, cnt_in, gsum, gcnt);
    build_kernel<<<(N_EDGES + 255) / 256, 256, 0, stream>>>(src, dst, deg_out_i, cnt_in, slots, N_EDGES);
    prep_kernel<<<(4 * DIM * DIM + 255) / 256, 256, 0, stream>>>(deg_out_i, cnt_in, norm_src, norm_dst, conv_W, wbfT);
    scale_x_kernel<<<(N_NODES * (DIM / 8) + 255) / 256, 256, 0, stream>>>(x, norm_src, h8a);

    const int conv_blocks = N_NODES / 16;   // 3125

    // conv0..2: fused spmm+gemm, fp8 out (relu, *norm_src)
    conv_fused_kernel<<<conv_blocks, 256, 0, stream>>>(cnt_in, slots, h8a, norm_dst,
        wbfT + 0 * DIM * DIM, conv_b + 0 * DIM, h8b, (unsigned short*)nullptr, norm_src, 1);
    conv_fused_kernel<<<conv_blocks, 256, 0, stream>>>(cnt_in, slots, h8b, norm_dst,
        wbfT + 1 * DIM * DIM, conv_b + 1 * DIM, h8a, (unsigned short*)nullptr, norm_src, 1);
    conv_fused_kernel<<<conv_blocks, 256, 0, stream>>>(cnt_in, slots, h8a, norm_dst,
        wbfT + 2 * DIM * DIM, conv_b + 2 * DIM, h8b, (unsigned short*)nullptr, norm_src, 1);
    // conv3: bf16 out, no relu, no scale
    conv_fused_kernel<<<conv_blocks, 256, 0, stream>>>(cnt_in, slots, h8b, norm_dst,
        wbfT + 3 * DIM * DIM, conv_b + 3 * DIM, (unsigned char*)nullptr, hP16, (const float*)nullptr, 0);

    // mean pool + head
    pool_kernel<<<(N_NODES + 255) / 256, 256, 0, stream>>>(hP16, graph_id, gsum, gcnt, N_NODES);
    mlp_kernel<<<N_GRAPHS, 128, 0, stream>>>(gsum, gcnt, ffnn_W, ffnn_b, out_W, out_b, out);
}